// Round 9
// baseline (173.418 us; speedup 1.0000x reference)
//
#include <hip/hip_runtime.h>
#include <hip/hip_bf16.h>
#include <stdint.h>

// Problem constants
#define D_MODEL 1024
#define BATCH   4
#define SEQ     4096
#define M_TOTAL (BATCH*SEQ)   // 16384
#define KDIM    1024
#define NTOT    2048          // combined N (z cols 0..1023, h cols 1024..2047)

// Scan chunking
#define NC 128
#define CL (SEQ/NC)           // 32

// GEMM tiling: round-2 structure (best measured), 32x32x16 MFMA inner loop
#define BM 256
#define BN 256
#define BK 32
#define NT (KDIM/BK)          // 32 K-tiles

typedef __bf16 bf16x8 __attribute__((ext_vector_type(8)));
typedef float  f32x4  __attribute__((ext_vector_type(4)));
typedef float  f32x16 __attribute__((ext_vector_type(16)));
typedef unsigned short u16x4 __attribute__((ext_vector_type(4)));

static __device__ __forceinline__ unsigned short f2bf(float f) {
  unsigned u = __builtin_bit_cast(unsigned, f);
  u += 0x7FFFu + ((u >> 16) & 1u);     // round-to-nearest-even
  return (unsigned short)(u >> 16);
}
static __device__ __forceinline__ float bf2f(unsigned short u) {
  return __builtin_bit_cast(float, (unsigned)u << 16);
}

// ---------------- K0a: x (fp32) -> bf16 ----------------
__global__ __launch_bounds__(256) void k_cvt_x(const float* __restrict__ x,
                                               unsigned short* __restrict__ xb) {
  int i = blockIdx.x * 256 + threadIdx.x;          // 4 elems each
  float4 v = ((const float4*)x)[i];
  ushort4 o;
  o.x = f2bf(v.x); o.y = f2bf(v.y); o.z = f2bf(v.z); o.w = f2bf(v.w);
  ((ushort4*)xb)[i] = o;
}

// ---------------- K0b: W (fp32 [d][e]) -> bf16 transposed [e][d] ----------------
__global__ void k_cvt_wT(const float* __restrict__ Wz, const float* __restrict__ Wh,
                         unsigned short* __restrict__ WzT, unsigned short* __restrict__ WhT) {
  __shared__ float tile[32][33];
  const float* W = blockIdx.z ? Wh : Wz;
  unsigned short* O = blockIdx.z ? WhT : WzT;
  int bx = blockIdx.x * 32;   // e base
  int by = blockIdx.y * 32;   // d base
  int tx = threadIdx.x, ty = threadIdx.y; // 32 x 8
  for (int yy = ty; yy < 32; yy += 8)
    tile[yy][tx] = W[(size_t)(by + yy) * D_MODEL + bx + tx];
  __syncthreads();
  for (int yy = ty; yy < 32; yy += 8)
    O[(size_t)(bx + yy) * D_MODEL + by + tx] = f2bf(tile[tx][yy]);
}

// ---------------- K1: GEMM  [P|Q](bf16) = xb @ Wall^T --------------------------
// EXACT round-2 skeleton (best measured: triple-buffered BK=32, depth-2
// prefetch, counted vmcnt(4), 8 waves of 128x64, frag-major conflict-free LDS,
// identical staging & barriers) with the MFMA cluster swapped to 32x32x16:
//   same 12 ds_read_b128/wave/K-step, but 16 MFMAs (8.07cyc) instead of 32
//   (4.85cyc) -> MFMA floor 1240->1032 cyc, half the issue slots.
// D-layout + packed epilogue reuse R5's refcheck-validated mapping.
__global__ __launch_bounds__(512, 2) void k_gemm8(
    const unsigned short* __restrict__ xb,    // [M][K] bf16
    const unsigned short* __restrict__ Wall,  // [2048][K] bf16 ([WzT;WhT])
    unsigned short* __restrict__ P, unsigned short* __restrict__ Q)
{
  __shared__ __attribute__((aligned(16))) unsigned short lds[3 * 16384]; // 96 KB

  const int tid  = threadIdx.x;
  const int wave = tid >> 6;
  const int lane = tid & 63;
  const int m0 = blockIdx.x * BM;
  const int n0 = blockIdx.y * BN;
  const int wr = wave >> 2;            // 0..1  (128 rows each)
  const int wc = wave & 3;             // 0..3  (64 cols each)
  const int l31 = lane & 31;
  const int lh  = lane >> 5;           // k-subchunk within fragment

  // staging pair coords (wave-uniform): pair p -> chunk p>>2, rowblock p&3
  const int p0 = wave * 2, p1 = wave * 2 + 1;
  const int c0 = p0 >> 2, rb0 = p0 & 3;
  const int c1 = p1 >> 2, rb1 = p1 & 3;

  f32x16 acc[4][2];
  #pragma unroll
  for (int i = 0; i < 4; ++i)
    #pragma unroll
    for (int j = 0; j < 2; ++j) acc[i][j] = (f32x16){0.f};

  auto stage = [&](int kt, int bufb) {
    const int kb = kt * BK;
    unsigned short* ldsA = &lds[bufb * 16384];
    unsigned short* ldsB = ldsA + 8192;
    const unsigned short* a0 = xb   + (size_t)(m0 + rb0*64 + lane) * KDIM + kb + c0*8;
    const unsigned short* a1 = xb   + (size_t)(m0 + rb1*64 + lane) * KDIM + kb + c1*8;
    const unsigned short* b0 = Wall + (size_t)(n0 + rb0*64 + lane) * KDIM + kb + c0*8;
    const unsigned short* b1 = Wall + (size_t)(n0 + rb1*64 + lane) * KDIM + kb + c1*8;
    __builtin_amdgcn_global_load_lds((const __attribute__((address_space(1))) unsigned int*)a0,
        (__attribute__((address_space(3))) unsigned int*)(ldsA + (c0*256 + rb0*64)*8), 16, 0, 0);
    __builtin_amdgcn_global_load_lds((const __attribute__((address_space(1))) unsigned int*)a1,
        (__attribute__((address_space(3))) unsigned int*)(ldsA + (c1*256 + rb1*64)*8), 16, 0, 0);
    __builtin_amdgcn_global_load_lds((const __attribute__((address_space(1))) unsigned int*)b0,
        (__attribute__((address_space(3))) unsigned int*)(ldsB + (c0*256 + rb0*64)*8), 16, 0, 0);
    __builtin_amdgcn_global_load_lds((const __attribute__((address_space(1))) unsigned int*)b1,
        (__attribute__((address_space(3))) unsigned int*)(ldsB + (c1*256 + rb1*64)*8), 16, 0, 0);
  };

  // prologue: tiles 0,1 in flight; wait tile 0 landed (tile 1's 4 loads may fly)
  stage(0, 0);
  stage(1, 1);
  asm volatile("s_waitcnt vmcnt(4)" ::: "memory");
  __builtin_amdgcn_s_barrier();

  // fragment base offsets (shorts): kc = kh*2 + lh selects the 256-row block
  const int aBase = (wr * 128 + l31) * 8;   // + kc*2048 + mf*256
  const int bBase = (wc * 64  + l31) * 8;   // + kc*2048 + nf*256

  int buf = 0;
  for (int kt = 0; kt < NT; ++kt) {
    // prefetch tile kt+2 into the buffer freed at the last barrier
    if (kt + 2 < NT) {
      int db = buf + 2; if (db >= 3) db -= 3;
      stage(kt + 2, db);
    }

    const unsigned short* bufA = &lds[buf * 16384];
    const unsigned short* bufB = bufA + 8192;

    #pragma unroll
    for (int kh = 0; kh < 2; ++kh) {
      const int kc = kh * 2 + lh;
      bf16x8 bfr[2], afr[4];
      #pragma unroll
      for (int nf = 0; nf < 2; ++nf)
        bfr[nf] = *(const bf16x8*)(bufB + kc * 2048 + bBase + nf * 256);
      #pragma unroll
      for (int mf = 0; mf < 4; ++mf)
        afr[mf] = *(const bf16x8*)(bufA + kc * 2048 + aBase + mf * 256);

      __builtin_amdgcn_s_setprio(1);
      #pragma unroll
      for (int mf = 0; mf < 4; ++mf)
        #pragma unroll
        for (int nf = 0; nf < 2; ++nf)
          acc[mf][nf] = __builtin_amdgcn_mfma_f32_32x32x16_bf16(
              bfr[nf], afr[mf], acc[mf][nf], 0, 0, 0);
      __builtin_amdgcn_s_setprio(0);
    }

    // counted wait: newest 4 loads (tile kt+2) may stay in flight
    if (kt < NT - 2) asm volatile("s_waitcnt vmcnt(4)" ::: "memory");
    else             asm volatile("s_waitcnt vmcnt(0)" ::: "memory");
    __builtin_amdgcn_s_barrier();
    buf = (buf == 2) ? 0 : buf + 1;
  }

  // epilogue (swapped-operand 32x32 D layout — refcheck-validated in R5):
  //   row m = m0 + wr*128 + mf*32 + (lane&31)
  //   col n = colb + wc*64 + nf*32 + g*8 + lh*4 + r  (regs g*4..g*4+3)
  unsigned short* Cout = (n0 < 1024) ? P : Q;
  const int colb = (n0 < 1024) ? n0 : (n0 - 1024);
  #pragma unroll
  for (int mf = 0; mf < 4; ++mf) {
    const size_t row = (size_t)(m0 + wr * 128 + mf * 32 + l31);
    #pragma unroll
    for (int nf = 0; nf < 2; ++nf) {
      #pragma unroll
      for (int g = 0; g < 4; ++g) {
        const size_t ncol = (size_t)(colb + wc * 64 + nf * 32 + g * 8 + lh * 4);
        u16x4 pk;
        pk[0] = f2bf(acc[mf][nf][g * 4 + 0]);
        pk[1] = f2bf(acc[mf][nf][g * 4 + 1]);
        pk[2] = f2bf(acc[mf][nf][g * 4 + 2]);
        pk[3] = f2bf(acc[mf][nf][g * 4 + 3]);
        *(u16x4*)(Cout + row * D_MODEL + ncol) = pk;
      }
    }
  }
}

// ---------------- K2: per-chunk scan aggregates (bf16 preacts) -----------------
__global__ __launch_bounds__(256) void k_scan_agg(
    const unsigned short* __restrict__ P, const unsigned short* __restrict__ Q,
    const float* __restrict__ bz, const float* __restrict__ bh,
    float* __restrict__ Aagg, float* __restrict__ Bagg)
{
  int c = blockIdx.x & (NC - 1);
  int b = blockIdx.x >> 7;
  int d = threadIdx.x * 4;
  f32x4 vbz = *(const f32x4*)(bz + d);
  f32x4 vbh = *(const f32x4*)(bh + d);
  f32x4 A = {1.f, 1.f, 1.f, 1.f}, Bv = {0.f, 0.f, 0.f, 0.f};
  size_t base = ((size_t)b * SEQ + (size_t)c * CL) * D_MODEL + d;
  for (int t = 0; t < CL; ++t) {
    u16x4 pu = *(const u16x4*)(P + base + (size_t)t * D_MODEL);
    u16x4 qu = *(const u16x4*)(Q + base + (size_t)t * D_MODEL);
    #pragma unroll
    for (int r = 0; r < 4; ++r) {
      float z = 1.f / (1.f + __expf(-(bf2f(pu[r]) + vbz[r])));
      float a = 1.f - z;
      float bb = z * (bf2f(qu[r]) + vbh[r]);
      Bv[r] = a * Bv[r] + bb;
      A[r]  = a * A[r];
    }
  }
  size_t o = ((size_t)b * NC + c) * D_MODEL + d;
  *(f32x4*)(Aagg + o) = A;
  *(f32x4*)(Bagg + o) = Bv;
}

// ---------------- K3: scan across chunk aggregates ----------------
__global__ __launch_bounds__(256) void k_scan_chunks(
    const float* __restrict__ Aagg, const float* __restrict__ Bagg,
    float* __restrict__ Pref)
{
  int idx = blockIdx.x * 256 + threadIdx.x;  // b*1024 + d
  int b = idx >> 10, d = idx & 1023;
  float h = 0.f;
  for (int cc = 0; cc < NC; ++cc) {
    size_t o = ((size_t)b * NC + cc) * D_MODEL + d;
    Pref[o] = h;
    h = Aagg[o] * h + Bagg[o];
  }
}

// ---------------- K4: apply scan, write fp32 h to d_out ----------------
__global__ __launch_bounds__(256) void k_scan_apply(
    const unsigned short* __restrict__ P, const unsigned short* __restrict__ Q,
    const float* __restrict__ bz, const float* __restrict__ bh,
    const float* __restrict__ Pref, float* __restrict__ out)
{
  int c = blockIdx.x & (NC - 1);
  int b = blockIdx.x >> 7;
  int d = threadIdx.x * 4;
  f32x4 vbz = *(const f32x4*)(bz + d);
  f32x4 vbh = *(const f32x4*)(bh + d);
  f32x4 h = *(const f32x4*)(Pref + ((size_t)b * NC + c) * D_MODEL + d);
  size_t base = ((size_t)b * SEQ + (size_t)c * CL) * D_MODEL + d;
  for (int t = 0; t < CL; ++t) {
    u16x4 pu = *(const u16x4*)(P + base + (size_t)t * D_MODEL);
    u16x4 qu = *(const u16x4*)(Q + base + (size_t)t * D_MODEL);
    #pragma unroll
    for (int r = 0; r < 4; ++r) {
      float z = 1.f / (1.f + __expf(-(bf2f(pu[r]) + vbz[r])));
      float a = 1.f - z;
      h[r] = a * h[r] + z * (bf2f(qu[r]) + vbh[r]);
    }
    *(f32x4*)(out + base + (size_t)t * D_MODEL) = h;
  }
}

extern "C" void kernel_launch(void* const* d_in, const int* in_sizes, int n_in,
                              void* d_out, int out_size, void* d_ws, size_t ws_size,
                              hipStream_t stream)
{
  const float* x  = (const float*)d_in[0];
  const float* Wz = (const float*)d_in[1];
  const float* bz = (const float*)d_in[2];
  const float* Wh = (const float*)d_in[3];
  const float* bh = (const float*)d_in[4];

  char* ws = (char*)d_ws;
  unsigned short* xb   = (unsigned short*)(ws);               // 33,554,432
  unsigned short* Wall = (unsigned short*)(ws + 33554432);    //  4,194,304 ([WzT;WhT])
  unsigned short* Pb   = (unsigned short*)(ws + 37748736);    // 33,554,432 (z-preact bf16)
  unsigned short* Qb   = (unsigned short*)(ws + 71303168);    // 33,554,432 (h-preact bf16)
  float* Aagg = (float*)(ws + 104857600);                     //  2,097,152
  float* Bagg = (float*)(ws + 106954752);                     //  2,097,152
  float* Pref = (float*)(ws + 109051904);                     //  2,097,152
  float* out  = (float*)d_out;

  k_cvt_x<<<M_TOTAL * D_MODEL / 4 / 256, 256, 0, stream>>>(x, xb);
  k_cvt_wT<<<dim3(32, 32, 2), dim3(32, 8), 0, stream>>>(Wz, Wh, Wall, Wall + (size_t)1024 * 1024);
  k_gemm8<<<dim3(M_TOTAL / BM, NTOT / BN), 512, 0, stream>>>(xb, Wall, Pb, Qb);
  k_scan_agg<<<BATCH * NC, 256, 0, stream>>>(Pb, Qb, bz, bh, Aagg, Bagg);
  k_scan_chunks<<<BATCH * D_MODEL / 256, 256, 0, stream>>>(Aagg, Bagg, Pref);
  k_scan_apply<<<BATCH * NC, 256, 0, stream>>>(Pb, Qb, bz, bh, Pref, out);
}